// Round 24
// baseline (2353.721 us; speedup 1.0000x reference)
//
#include <hip/hip_runtime.h>
#include <hip/hip_bf16.h>

typedef __bf16 bf16;
typedef __bf16 bf16x8 __attribute__((ext_vector_type(8)));
typedef float f32x4 __attribute__((ext_vector_type(4)));

#define N_ROWS   512      // rows 0..255 seq1, 256..511 seq2
#define HID      1024
#define KX       320      // EMB=300 padded to 320
#define KTOT     1344     // 320 + 1024
#define NSTEPS   128
#define EMB_D    300
#define HC_W     3332     // 1025+1025+1+1025+256

// workspace layout (bytes) — lstm phase:
#define WBT_OFF   0UL          // bf16 [4096][1344]  (packed p2 order)
#define XB_OFF    11010048UL   // bf16 [128][512][320]
#define HB_OFF    52953088UL   // bf16 [2][512][1024]
#define BIASP_OFF 55050240UL   // f32  [4096] (packed p2 order)
#define CB_OFF    55066624UL   // f32  [512][1024] cell state
// head phase (aliases Xb, dead after the recurrence):
#define HC_OFF    11010048UL   // f32 [256][3332]           ends 14,422,016
#define H2T_OFF   14422016UL   // f32 [1025][256]           ends 15,471,616
#define T1P_OFF   15471616UL   // f32 [4][256][1025]        ends 19,670,016
#define E1P_OFF   19670016UL   // f32 [8][256][512]         ends 23,864,320
#define IP_OFF    23864320UL   // f32 [2][256][256]         ends 24,388,608

// r18-proven: NO cooperative kernel; 128 graph-captured per-step launches.
// r23-proven: 2 blocks/CU overlap wins in launch mode.
// r24: one step further — 32 rows x 64 pcols, 128-thread blocks, grid 1024
// -> 4 blocks/CU (24 KB LDS). r23 (grid 512) is the fallback.

__device__ __forceinline__ float sigm(float x) { return 1.f / (1.f + __expf(-x)); }
__device__ __forceinline__ float tanh_fast(float x) {
  float xc = fminf(fmaxf(x, -15.f), 15.f);
  float e = __expf(2.f * xc);
  return (e - 1.f) / (e + 1.f);
}

// LDS-only barrier (r14-proven): does not drain vmcnt.
__device__ __forceinline__ void lds_barrier() {
  asm volatile("s_waitcnt lgkmcnt(0)" ::: "memory");
  __builtin_amdgcn_sched_barrier(0);
  __builtin_amdgcn_s_barrier();
  __builtin_amdgcn_sched_barrier(0);
}

// ---- pack kernels -------------------------------------------------------
// packed order: p2 = cb*64 + g*16 + c  <->  orig col g*1024 + cb*16 + c
// v3 (r20-proven): LDS-transpose tiles, coalesced reads, contiguous writes.
__global__ void pack_wbt(const float* __restrict__ lk, bf16* __restrict__ wbt) {
  __shared__ float sh[64][65];
  const int px = blockIdx.x;       // cb 0..63
  const int k0 = blockIdx.y * 64;  // 21 tiles
  const int t = threadIdx.x;
  {
    const int kk = t >> 2, g = t & 3;
    const int k = k0 + kk;
    const bool valid = (k < KX) ? (k < EMB_D) : true;
    const int src = (k < KX) ? k : (k - 20);
    const float* base = lk + (size_t)src * 4096 + g * 1024 + px * 16;
#pragma unroll
    for (int c4 = 0; c4 < 4; ++c4) {
      float4 v = valid ? *reinterpret_cast<const float4*>(base + c4 * 4)
                       : float4{0.f, 0.f, 0.f, 0.f};
      sh[kk][g * 16 + c4 * 4 + 0] = v.x;
      sh[kk][g * 16 + c4 * 4 + 1] = v.y;
      sh[kk][g * 16 + c4 * 4 + 2] = v.z;
      sh[kk][g * 16 + c4 * 4 + 3] = v.w;
    }
  }
  __syncthreads();
  {
    const int pl = t >> 2, kq = (t & 3) * 16;
    bf16 ov[16];
#pragma unroll
    for (int j = 0; j < 16; ++j) ov[j] = (bf16)sh[kq + j][pl];
    bf16* dst = wbt + (size_t)(px * 64 + pl) * KTOT + k0 + kq;
#pragma unroll
    for (int j = 0; j < 2; ++j)
      *reinterpret_cast<bf16x8*>(dst + j * 8) =
          *reinterpret_cast<const bf16x8*>(&ov[j * 8]);
  }
}

// vectorized bf16x8 writes; block 320 = 8 timesteps x 40 e-groups (r11-proven)
__global__ void pack_xb(const int* __restrict__ in1, const int* __restrict__ in2,
                        const float* __restrict__ emb, bf16* __restrict__ xb) {
  int r = blockIdx.x;                        // 0..511
  int t = blockIdx.y * 8 + threadIdx.x / 40; // 0..127
  int e8 = threadIdx.x % 40;                 // 0..39 (8 elems each)
  int tok = (r < 256) ? in1[r * 128 + t] : in2[(r - 256) * 128 + t];
  const float* er = emb + (size_t)tok * EMB_D + e8 * 8;
  bf16x8 v;
  if (e8 < 37) {
#pragma unroll
    for (int i = 0; i < 8; ++i) v[i] = (bf16)er[i];
  } else {
#pragma unroll
    for (int i = 0; i < 8; ++i) {
      int e = e8 * 8 + i;
      v[i] = (e < EMB_D) ? (bf16)er[i] : (bf16)0.f;
    }
  }
  *reinterpret_cast<bf16x8*>(&xb[((size_t)t * N_ROWS + r) * KX + e8 * 8]) = v;
}

__global__ void pack_misc(const float* __restrict__ h1i, const float* __restrict__ h2i,
                          const float* __restrict__ c1i, const float* __restrict__ c2i,
                          const float* __restrict__ bias, bf16* __restrict__ hb0,
                          float* __restrict__ biasp, float* __restrict__ Cb) {
  int idx = blockIdx.x * 256 + threadIdx.x;
  if (idx < N_ROWS * HID) {
    int r = idx >> 10, k = idx & 1023;
    float v = (r < 256) ? h1i[(size_t)r * HID + k] : h2i[(size_t)(r - 256) * HID + k];
    hb0[idx] = (bf16)v;
    float cv = (r < 256) ? c1i[(size_t)r * HID + k] : c2i[(size_t)(r - 256) * HID + k];
    Cb[idx] = cv;
  }
  if (idx < 4096) {
    int cb = idx >> 6, g = (idx >> 4) & 3, c = idx & 15;
    biasp[idx] = bias[g * HID + cb * 16 + c];
  }
}

// ---- per-step LSTM kernel (r24: 32 rows x 64 pcols, 4 blocks/CU) --------
// grid 1024 = 16 row-blocks x 64 col-groups; block 128 threads = 2 waves.
// Wave w owns rows w*16..+15 (r15/r23-proven mapping):
//   acc[ni][q] = G[row=w*16+(lane>>4)*4+q][pcol=ni*16+(lane&15)]
//   gate = ni, cell = cb*16 + (lane&15): cell update fully in-register.
__launch_bounds__(128, 4)
__global__ void lstm_step(const bf16* __restrict__ xb, const bf16* __restrict__ wbt,
                          bf16* __restrict__ hb, const float* __restrict__ biasp,
                          float* __restrict__ Cb, const int* __restrict__ s1,
                          const int* __restrict__ s2, int t) {
  __shared__ bf16 As[2][32][64];     //  8 KB, XOR-swizzled 16B chunks
  __shared__ bf16 Bs[2][64][64];     // 16 KB  (total 24 KB)
  const int tid = threadIdx.x;
  const int wave = tid >> 6;       // 0..1
  const int lane = tid & 63;
  const int lrow = lane & 15;
  const int hi = lane >> 4;        // 0..3
  const int l7 = lane & 7;
  const int bid = blockIdx.x;
  const int rb = bid >> 6;         // 0..15
  const int cb = bid & 63;         // 0..63
  const int r0 = rb * 32;

  const int cellabs = cb * 16 + lrow;    // this lane's cell column (0..1023)

  int slen[4];        // per q: row = r0 + wave*16 + hi*4 + q
#pragma unroll
  for (int q = 0; q < 4; ++q) {
    int rr = r0 + wave * 16 + hi * 4 + q;
    slen[q] = (rr < 256) ? s1[rr] : s2[rr - 256];
  }

  float creg[4];      // cell state from global
#pragma unroll
  for (int q = 0; q < 4; ++q) {
    int rr = r0 + wave * 16 + hi * 4 + q;
    creg[q] = Cb[(size_t)rr * HID + cellabs];
  }

  float bv[4];        // bias per gate for this lane's cell
#pragma unroll
  for (int ni = 0; ni < 4; ++ni)
    bv[ni] = biasp[cb * 64 + ni * 16 + lrow];

  // staging with 128 threads:
  //   A: 32 rows x 8 chunks -> a_r = tid>>2 (0..31), chunks (tid&3)*2 + q, q<2
  //   B: 64 rows x 8 chunks -> b_r = tid>>1 (0..63), chunks (tid&1)*4 + q, q<4
  // XOR swizzle: chunk cc -> col ((cc ^ (row&7)) << 3).
  const int a_r = tid >> 2, a_cb = (tid & 3) * 2;
  const int b_r = tid >> 1, b_cb = (tid & 1) * 4;

  const bf16* xt = xb + (size_t)t * N_ROWS * KX;
  const bf16* hc0 = hb + ((size_t)(t & 1) << 19);

  bf16x8 ra[2], rbv4[4];
  auto issue_loads = [&](int nkc) {
    const bf16* asrc = (nkc < 5)
        ? (xt + (size_t)(r0 + a_r) * KX + nkc * 64 + a_cb * 8)
        : (hc0 + ((size_t)(r0 + a_r) << 10) + (nkc * 64 - KX) + a_cb * 8);
#pragma unroll
    for (int q = 0; q < 2; ++q)
      ra[q] = *reinterpret_cast<const bf16x8*>(asrc + q * 8);
    const bf16* bsrc = wbt + (size_t)(cb * 64 + b_r) * KTOT + nkc * 64 + b_cb * 8;
#pragma unroll
    for (int q = 0; q < 4; ++q)
      rbv4[q] = *reinterpret_cast<const bf16x8*>(bsrc + q * 8);
  };
  auto stage_to = [&](int buf) {
#pragma unroll
    for (int q = 0; q < 2; ++q)
      *reinterpret_cast<bf16x8*>(&As[buf][a_r][((a_cb + q) ^ (a_r & 7)) << 3]) = ra[q];
#pragma unroll
    for (int q = 0; q < 4; ++q)
      *reinterpret_cast<bf16x8*>(&Bs[buf][b_r][((b_cb + q) ^ (b_r & 7)) << 3]) = rbv4[q];
  };

  issue_loads(0);
  stage_to(0);
  issue_loads(1);
  __syncthreads();
  int db = 0;

  f32x4 acc[4];
#pragma unroll
  for (int ni = 0; ni < 4; ++ni)
    acc[ni] = f32x4{bv[ni], bv[ni], bv[ni], bv[ni]};

  for (int kc = 0; kc < 21; ++kc) {
    if (kc < 20) stage_to(db ^ 1);
    {
      int nkc = kc + 2;
      if (nkc <= 20) issue_loads(nkc);
    }
    // compute chunk kc: per ks, 1 A-frag + 4 B-frags, 4 MFMAs
#pragma unroll
    for (int ks = 0; ks < 2; ++ks) {
      const int cs = (((ks << 2) | hi) ^ l7) << 3;
      bf16x8 af = *reinterpret_cast<const bf16x8*>(&As[db][wave * 16 + lrow][cs]);
#pragma unroll
      for (int ni = 0; ni < 4; ++ni) {
        bf16x8 bfv = *reinterpret_cast<const bf16x8*>(&Bs[db][ni * 16 + lrow][cs]);
        acc[ni] = __builtin_amdgcn_mfma_f32_16x16x32_bf16(af, bfv, acc[ni], 0, 0, 0);
      }
    }
    lds_barrier();
    db ^= 1;
  }

  // cell update: lane owns 4 rows x 1 cell, all 4 gates in-register (g=ni)
  {
    const bf16* hc = hc0;
    bf16* hnb = hb + (((size_t)(t & 1) << 19) ^ ((size_t)1 << 19));
#pragma unroll
    for (int q = 0; q < 4; ++q) {
      float ig = acc[0][q];
      float jg = acc[1][q];
      float fg = acc[2][q];
      float og = acc[3][q];
      float cn = sigm(fg + 1.f) * creg[q] + sigm(ig) * tanh_fast(jg);
      float hv = tanh_fast(cn) * sigm(og);
      int rr = r0 + wave * 16 + hi * 4 + q;
      size_t off = ((size_t)rr << 10) + cellabs;
      float ho;
      if (t < slen[q]) {
        Cb[off] = cn;
        ho = hv;
      } else {
        ho = (float)hc[off];
      }
      hnb[off] = (bf16)ho;
    }
  }
}

// ---- head ---------------------------------------------------------------
__global__ void feat_kernel(const bf16* __restrict__ hb0, const int* __restrict__ s1,
                            const int* __restrict__ s2, float* __restrict__ HC,
                            float* __restrict__ H2T) {
  int a = blockIdx.x;
  int tid = threadIdx.x;
  __shared__ float red[256];
  const bf16* h1r = hb0 + (size_t)a * HID;
  const bf16* h2r = hb0 + (size_t)(a + 256) * HID;
  float l1 = (float)s1[a] * (1.f / 128.f);
  float l2 = (float)s2[a] * (1.f / 128.f);
  float dacc = 0.f;
  for (int k = tid; k < 1025; k += 256) {
    float v1 = (k < HID) ? (float)h1r[k] : l1;
    float v2 = (k < HID) ? (float)h2r[k] : l2;
    HC[(size_t)a * HC_W + k] = v1;
    HC[(size_t)a * HC_W + 1025 + k] = v2;
    HC[(size_t)a * HC_W + 2051 + k] = v1 * v2;
    H2T[(size_t)k * 256 + a] = v2;
    float d = v1 - v2;
    dacc += d * d;
  }
  red[tid] = dacc;
  __syncthreads();
  for (int s = 128; s > 0; s >>= 1) {
    if (tid < s) red[tid] += red[tid + s];
    __syncthreads();
  }
  if (tid == 0) HC[(size_t)a * HC_W + 2050] = red[0];
}

// r22-proven: 2 rows/block, K-split x4 (z=0..3: 257,256,256,256).
__global__ void t1_kernel(const float* __restrict__ HC, const float* __restrict__ Wh,
                          float* __restrict__ T1p) {
  int j = blockIdx.x * 256 + threadIdx.x;
  int a0 = blockIdx.y * 2;
  int z = blockIdx.z;
  const int k0 = (z == 0) ? 0 : (257 + 256 * (z - 1));
  const int kn = (z == 0) ? 257 : 256;
  __shared__ float sh[2][257];
  for (int idx = threadIdx.x; idx < 2 * kn; idx += 256) {
    int r = (idx >= kn) ? 1 : 0;
    int k = idx - r * kn;
    sh[r][k] = HC[(size_t)(a0 + r) * HC_W + k0 + k];
  }
  __syncthreads();
  if (j < 1025) {
    float acc0 = 0.f, acc1 = 0.f;
    for (int k = 0; k < kn; ++k) {
      float w = Wh[(size_t)(k0 + k) * 1025 + j];
      acc0 += sh[0][k] * w;
      acc1 += sh[1][k] * w;
    }
    float* T1 = T1p + (size_t)z * 256 * 1025;
    T1[(size_t)a0 * 1025 + j] = acc0;
    T1[(size_t)(a0 + 1) * 1025 + j] = acc1;
  }
}

// r22-proven: 1 row/block, K-split x2 (y: 513/512). Writes IP[z].
__global__ void inter_kernel(const float* __restrict__ T1p,
                             const float* __restrict__ H2T, float* __restrict__ IP) {
  int a = blockIdx.x;
  int z = blockIdx.y;
  int b = threadIdx.x;
  const int k0 = z ? 513 : 0;
  const int kn = z ? 512 : 513;
  const size_t zs = (size_t)256 * 1025;
  __shared__ float sT[513];
  for (int k = threadIdx.x; k < kn; k += 256) {
    size_t off = (size_t)a * 1025 + k0 + k;
    sT[k] = T1p[off] + T1p[off + zs] + T1p[off + 2 * zs] + T1p[off + 3 * zs];
  }
  __syncthreads();
  float acc = 0.f;
  for (int k = 0; k < kn; ++k)
    acc += sT[k] * H2T[(size_t)(k0 + k) * 256 + b];
  IP[(size_t)z * 256 * 256 + (size_t)a * 256 + b] = acc;
}

// r23-proven: 2 rows/block, K-split x8 (z, 417 each; z=7: 413).
// z==7 covers gk in [2919,3332): interaction cols [3076,3332) read from
// IP0+IP1 instead of HC.
__global__ void e1_kernel(const float* __restrict__ HC, const float* __restrict__ W1,
                          const float* __restrict__ IP, float* __restrict__ E1p) {
  int a0 = blockIdx.x * 2;
  int j = blockIdx.y * 256 + threadIdx.x;
  int z = blockIdx.z;
  const int k0 = z * 417;
  const int kn = (z == 7) ? 413 : 417;
  const size_t ips = (size_t)256 * 256;
  __shared__ float sh[2][417];
  for (int idx = threadIdx.x; idx < 2 * kn; idx += 256) {
    int r = (idx >= kn) ? 1 : 0;
    int k = idx - r * kn;
    int gk = k0 + k;
    float v;
    if (z == 7 && gk >= 3076) {
      size_t off = (size_t)(a0 + r) * 256 + (gk - 3076);
      v = IP[off] + IP[off + ips];
    } else {
      v = HC[(size_t)(a0 + r) * HC_W + gk];
    }
    sh[r][k] = v;
  }
  __syncthreads();
  float acc0 = 0.f, acc1 = 0.f;
  for (int k = 0; k < kn; ++k) {
    float w = W1[(size_t)(k0 + k) * 512 + j];
    acc0 += sh[0][k] * w;
    acc1 += sh[1][k] * w;
  }
  float* E1 = E1p + (size_t)z * 256 * 512;
  E1[(size_t)a0 * 512 + j] = acc0;
  E1[(size_t)(a0 + 1) * 512 + j] = acc1;
}

// r23-proven: e1 = relu(sum_{z<8} E1p[z] + b1); then W2 reduce. grid 256.
__global__ void out_kernel(const float* __restrict__ E1p,
                           const float* __restrict__ b1, const float* __restrict__ W2,
                           const float* __restrict__ b2, float* __restrict__ out) {
  int a = blockIdx.x;
  int tid = threadIdx.x;
  __shared__ float red0[256], red1[256];
  const size_t zs = (size_t)256 * 512;
  size_t i0 = (size_t)a * 512 + tid;
  size_t i1 = i0 + 256;
  float s0 = 0.f, s1 = 0.f;
#pragma unroll
  for (int z = 0; z < 8; ++z) {
    s0 += E1p[i0 + z * zs];
    s1 += E1p[i1 + z * zs];
  }
  float v0 = fmaxf(s0 + b1[tid], 0.f);
  float v1 = fmaxf(s1 + b1[tid + 256], 0.f);
  float a0 = v0 * W2[2 * tid] + v1 * W2[2 * (tid + 256)];
  float a1 = v0 * W2[2 * tid + 1] + v1 * W2[2 * (tid + 256) + 1];
  red0[tid] = a0;
  red1[tid] = a1;
  __syncthreads();
  for (int s = 128; s > 0; s >>= 1) {
    if (tid < s) { red0[tid] += red0[tid + s]; red1[tid] += red1[tid + s]; }
    __syncthreads();
  }
  if (tid == 0) {
    out[2 * a] = red0[0] + b2[0];
    out[2 * a + 1] = red1[0] + b2[1];
  }
}

// ---- host ---------------------------------------------------------------
extern "C" void kernel_launch(void* const* d_in, const int* in_sizes, int n_in,
                              void* d_out, int out_size, void* d_ws, size_t ws_size,
                              hipStream_t stream) {
  const int*   input1 = (const int*)d_in[0];
  const int*   input2 = (const int*)d_in[1];
  const int*   seql1  = (const int*)d_in[2];
  const int*   seql2  = (const int*)d_in[3];
  const float* emb    = (const float*)d_in[4];
  const float* lk     = (const float*)d_in[5];
  const float* lbias  = (const float*)d_in[6];
  const float* c1i    = (const float*)d_in[7];
  const float* h1i    = (const float*)d_in[8];
  const float* c2i    = (const float*)d_in[9];
  const float* h2i    = (const float*)d_in[10];
  const float* W_h    = (const float*)d_in[11];
  const float* W1     = (const float*)d_in[12];
  const float* b1     = (const float*)d_in[13];
  const float* W2     = (const float*)d_in[14];
  const float* b2     = (const float*)d_in[15];

  char* ws = (char*)d_ws;
  bf16*     WbT   = (bf16*)(ws + WBT_OFF);
  bf16*     Xb    = (bf16*)(ws + XB_OFF);
  bf16*     Hb    = (bf16*)(ws + HB_OFF);
  float*    biasp = (float*)(ws + BIASP_OFF);
  float*    Cb    = (float*)(ws + CB_OFF);
  float*    HC    = (float*)(ws + HC_OFF);   // aliases Xb (dead after lstm)
  float*    H2T   = (float*)(ws + H2T_OFF);
  float*    T1p   = (float*)(ws + T1P_OFF);
  float*    E1p   = (float*)(ws + E1P_OFF);
  float*    IP    = (float*)(ws + IP_OFF);

  pack_wbt<<<dim3(64, 21), 256, 0, stream>>>(lk, WbT);
  pack_xb<<<dim3(512, 16), 320, 0, stream>>>(input1, input2, emb, Xb);
  pack_misc<<<2048, 256, 0, stream>>>(h1i, h2i, c1i, c2i, lbias, Hb, biasp, Cb);

  for (int t = 0; t < NSTEPS; ++t)
    lstm_step<<<1024, 128, 0, stream>>>(Xb, WbT, Hb, biasp, Cb, seql1, seql2, t);

  feat_kernel<<<256, 256, 0, stream>>>(Hb, seql1, seql2, HC, H2T);
  t1_kernel<<<dim3(5, 128, 4), 256, 0, stream>>>(HC, W_h, T1p);
  inter_kernel<<<dim3(256, 2), 256, 0, stream>>>(T1p, H2T, IP);
  e1_kernel<<<dim3(128, 2, 8), 256, 0, stream>>>(HC, W1, IP, E1p);
  out_kernel<<<256, 256, 0, stream>>>(E1p, b1, W2, b2, (float*)d_out);
}

// Round 25
// 2116.865 us; speedup vs baseline: 1.1119x; 1.1119x over previous
//
#include <hip/hip_runtime.h>
#include <hip/hip_bf16.h>

typedef __bf16 bf16;
typedef __bf16 bf16x8 __attribute__((ext_vector_type(8)));
typedef float f32x4 __attribute__((ext_vector_type(4)));

#define N_ROWS   512      // rows 0..255 seq1, 256..511 seq2
#define HID      1024
#define KX       320      // EMB=300 padded to 320
#define KTOT     1344     // 320 + 1024
#define NSTEPS   128
#define EMB_D    300
#define HC_W     3332     // 1025+1025+1+1025+256

// workspace layout (bytes) — lstm phase:
#define WBT_OFF   0UL          // bf16 [4096][1344]  (packed p2 order)
#define XB_OFF    11010048UL   // bf16 [128][512][320]
#define HB_OFF    52953088UL   // bf16 [2][512][1024]
#define BIASP_OFF 55050240UL   // f32  [4096] (packed p2 order)
#define CB_OFF    55066624UL   // f32  [512][1024] cell state
// head phase (aliases Xb, dead after the recurrence):
#define HC_OFF    11010048UL   // f32 [256][3332]           ends 14,422,016
#define H2T_OFF   14422016UL   // f32 [1025][256]           ends 15,471,616
#define T1P_OFF   15471616UL   // f32 [4][256][1025]        ends 19,670,016
#define E1P_OFF   19670016UL   // f32 [8][256][512]         ends 23,864,320
#define IP_OFF    23864320UL   // f32 [2][256][256]         ends 24,388,608

// r18-proven: NO cooperative kernel; 128 graph-captured per-step launches.
// r23-proven: lstm_step grid 512 (8 rb x 64 cb), 64x64, 2 blocks/CU optimum
// (r24's 4 blocks/CU regressed; reverted). r25: t1 1 row/block; feat split.

__device__ __forceinline__ float sigm(float x) { return 1.f / (1.f + __expf(-x)); }
__device__ __forceinline__ float tanh_fast(float x) {
  float xc = fminf(fmaxf(x, -15.f), 15.f);
  float e = __expf(2.f * xc);
  return (e - 1.f) / (e + 1.f);
}

// LDS-only barrier (r14-proven): does not drain vmcnt.
__device__ __forceinline__ void lds_barrier() {
  asm volatile("s_waitcnt lgkmcnt(0)" ::: "memory");
  __builtin_amdgcn_sched_barrier(0);
  __builtin_amdgcn_s_barrier();
  __builtin_amdgcn_sched_barrier(0);
}

// ---- pack kernels -------------------------------------------------------
// packed order: p2 = cb*64 + g*16 + c  <->  orig col g*1024 + cb*16 + c
// v3 (r20-proven): LDS-transpose tiles, coalesced reads, contiguous writes.
__global__ void pack_wbt(const float* __restrict__ lk, bf16* __restrict__ wbt) {
  __shared__ float sh[64][65];
  const int px = blockIdx.x;       // cb 0..63
  const int k0 = blockIdx.y * 64;  // 21 tiles
  const int t = threadIdx.x;
  {
    const int kk = t >> 2, g = t & 3;
    const int k = k0 + kk;
    const bool valid = (k < KX) ? (k < EMB_D) : true;
    const int src = (k < KX) ? k : (k - 20);
    const float* base = lk + (size_t)src * 4096 + g * 1024 + px * 16;
#pragma unroll
    for (int c4 = 0; c4 < 4; ++c4) {
      float4 v = valid ? *reinterpret_cast<const float4*>(base + c4 * 4)
                       : float4{0.f, 0.f, 0.f, 0.f};
      sh[kk][g * 16 + c4 * 4 + 0] = v.x;
      sh[kk][g * 16 + c4 * 4 + 1] = v.y;
      sh[kk][g * 16 + c4 * 4 + 2] = v.z;
      sh[kk][g * 16 + c4 * 4 + 3] = v.w;
    }
  }
  __syncthreads();
  {
    const int pl = t >> 2, kq = (t & 3) * 16;
    bf16 ov[16];
#pragma unroll
    for (int j = 0; j < 16; ++j) ov[j] = (bf16)sh[kq + j][pl];
    bf16* dst = wbt + (size_t)(px * 64 + pl) * KTOT + k0 + kq;
#pragma unroll
    for (int j = 0; j < 2; ++j)
      *reinterpret_cast<bf16x8*>(dst + j * 8) =
          *reinterpret_cast<const bf16x8*>(&ov[j * 8]);
  }
}

// vectorized bf16x8 writes; block 320 = 8 timesteps x 40 e-groups (r11-proven)
__global__ void pack_xb(const int* __restrict__ in1, const int* __restrict__ in2,
                        const float* __restrict__ emb, bf16* __restrict__ xb) {
  int r = blockIdx.x;                        // 0..511
  int t = blockIdx.y * 8 + threadIdx.x / 40; // 0..127
  int e8 = threadIdx.x % 40;                 // 0..39 (8 elems each)
  int tok = (r < 256) ? in1[r * 128 + t] : in2[(r - 256) * 128 + t];
  const float* er = emb + (size_t)tok * EMB_D + e8 * 8;
  bf16x8 v;
  if (e8 < 37) {
#pragma unroll
    for (int i = 0; i < 8; ++i) v[i] = (bf16)er[i];
  } else {
#pragma unroll
    for (int i = 0; i < 8; ++i) {
      int e = e8 * 8 + i;
      v[i] = (e < EMB_D) ? (bf16)er[i] : (bf16)0.f;
    }
  }
  *reinterpret_cast<bf16x8*>(&xb[((size_t)t * N_ROWS + r) * KX + e8 * 8]) = v;
}

__global__ void pack_misc(const float* __restrict__ h1i, const float* __restrict__ h2i,
                          const float* __restrict__ c1i, const float* __restrict__ c2i,
                          const float* __restrict__ bias, bf16* __restrict__ hb0,
                          float* __restrict__ biasp, float* __restrict__ Cb) {
  int idx = blockIdx.x * 256 + threadIdx.x;
  if (idx < N_ROWS * HID) {
    int r = idx >> 10, k = idx & 1023;
    float v = (r < 256) ? h1i[(size_t)r * HID + k] : h2i[(size_t)(r - 256) * HID + k];
    hb0[idx] = (bf16)v;
    float cv = (r < 256) ? c1i[(size_t)r * HID + k] : c2i[(size_t)(r - 256) * HID + k];
    Cb[idx] = cv;
  }
  if (idx < 4096) {
    int cb = idx >> 6, g = (idx >> 4) & 3, c = idx & 15;
    biasp[idx] = bias[g * HID + cb * 16 + c];
  }
}

// ---- per-step LSTM kernel (r23-proven, verbatim) ------------------------
// grid 512 = 8 row-blocks x 64 col-groups. Wave w owns rows w*16..+15:
//   acc[ni][q] = G[row=w*16+(lane>>4)*4+q][pcol=ni*16+(lane&15)]
//   gate = ni, cell = cb*16 + (lane&15): cell update fully in-register.
// LDS 32 KB -> 2 blocks/CU (proven optimum: 1->2 wins, 2->4 loses).
__launch_bounds__(256, 2)
__global__ void lstm_step(const bf16* __restrict__ xb, const bf16* __restrict__ wbt,
                          bf16* __restrict__ hb, const float* __restrict__ biasp,
                          float* __restrict__ Cb, const int* __restrict__ s1,
                          const int* __restrict__ s2, int t) {
  __shared__ bf16 As[2][64][64];     // 16 KB, XOR-swizzled 16B chunks
  __shared__ bf16 Bs[2][64][64];     // 16 KB  (total 32 KB)
  const int tid = threadIdx.x;
  const int wave = tid >> 6;
  const int lane = tid & 63;
  const int lrow = lane & 15;
  const int hi = lane >> 4;        // 0..3
  const int l7 = lane & 7;
  const int bid = blockIdx.x;
  const int rb = bid >> 6;         // 0..7
  const int cb = bid & 63;         // 0..63
  const int r0 = rb * 64;

  const int cellabs = cb * 16 + lrow;    // this lane's cell column (0..1023)

  int slen[4];        // per q: row = r0 + wave*16 + hi*4 + q
#pragma unroll
  for (int q = 0; q < 4; ++q) {
    int rr = r0 + wave * 16 + hi * 4 + q;
    slen[q] = (rr < 256) ? s1[rr] : s2[rr - 256];
  }

  float creg[4];      // cell state from global
#pragma unroll
  for (int q = 0; q < 4; ++q) {
    int rr = r0 + wave * 16 + hi * 4 + q;
    creg[q] = Cb[(size_t)rr * HID + cellabs];
  }

  float bv[4];        // bias per gate for this lane's cell
#pragma unroll
  for (int ni = 0; ni < 4; ++ni)
    bv[ni] = biasp[cb * 64 + ni * 16 + lrow];

  // staging: A/B 64 rows x 8 chunks, 4 threads/row, 2 chunks each.
  // XOR swizzle: chunk cc -> col ((cc ^ (row&7)) << 3).
  const int a_r = tid >> 2, a_cb = (tid & 3) * 2;

  const bf16* xt = xb + (size_t)t * N_ROWS * KX;
  const bf16* hc0 = hb + ((size_t)(t & 1) << 19);

  bf16x8 ra[2], rbv2[2];
  auto issue_loads = [&](int nkc) {
    const bf16* asrc = (nkc < 5)
        ? (xt + (size_t)(r0 + a_r) * KX + nkc * 64 + a_cb * 8)
        : (hc0 + ((size_t)(r0 + a_r) << 10) + (nkc * 64 - KX) + a_cb * 8);
#pragma unroll
    for (int q = 0; q < 2; ++q)
      ra[q] = *reinterpret_cast<const bf16x8*>(asrc + q * 8);
    const bf16* bsrc = wbt + (size_t)(cb * 64 + a_r) * KTOT + nkc * 64 + a_cb * 8;
#pragma unroll
    for (int q = 0; q < 2; ++q)
      rbv2[q] = *reinterpret_cast<const bf16x8*>(bsrc + q * 8);
  };
  auto stage_to = [&](int buf) {
#pragma unroll
    for (int q = 0; q < 2; ++q)
      *reinterpret_cast<bf16x8*>(&As[buf][a_r][((a_cb + q) ^ (a_r & 7)) << 3]) = ra[q];
#pragma unroll
    for (int q = 0; q < 2; ++q)
      *reinterpret_cast<bf16x8*>(&Bs[buf][a_r][((a_cb + q) ^ (a_r & 7)) << 3]) = rbv2[q];
  };

  issue_loads(0);
  stage_to(0);
  issue_loads(1);
  __syncthreads();
  int db = 0;

  f32x4 acc[4];
#pragma unroll
  for (int ni = 0; ni < 4; ++ni)
    acc[ni] = f32x4{bv[ni], bv[ni], bv[ni], bv[ni]};

  for (int kc = 0; kc < 21; ++kc) {
    if (kc < 20) stage_to(db ^ 1);
    {
      int nkc = kc + 2;
      if (nkc <= 20) issue_loads(nkc);
    }
    // compute chunk kc: per ks, 1 A-frag + 4 B-frags, 4 MFMAs
#pragma unroll
    for (int ks = 0; ks < 2; ++ks) {
      const int cs = (((ks << 2) | hi) ^ l7) << 3;
      bf16x8 af = *reinterpret_cast<const bf16x8*>(&As[db][wave * 16 + lrow][cs]);
#pragma unroll
      for (int ni = 0; ni < 4; ++ni) {
        bf16x8 bfv = *reinterpret_cast<const bf16x8*>(&Bs[db][ni * 16 + lrow][cs]);
        acc[ni] = __builtin_amdgcn_mfma_f32_16x16x32_bf16(af, bfv, acc[ni], 0, 0, 0);
      }
    }
    lds_barrier();
    db ^= 1;
  }

  // cell update: lane owns 4 rows x 1 cell, all 4 gates in-register (g=ni)
  {
    const bf16* hc = hc0;
    bf16* hnb = hb + (((size_t)(t & 1) << 19) ^ ((size_t)1 << 19));
#pragma unroll
    for (int q = 0; q < 4; ++q) {
      float ig = acc[0][q];
      float jg = acc[1][q];
      float fg = acc[2][q];
      float og = acc[3][q];
      float cn = sigm(fg + 1.f) * creg[q] + sigm(ig) * tanh_fast(jg);
      float hv = tanh_fast(cn) * sigm(og);
      int rr = r0 + wave * 16 + hi * 4 + q;
      size_t off = ((size_t)rr << 10) + cellabs;
      float ho;
      if (t < slen[q]) {
        Cb[off] = cn;
        ho = hv;
      } else {
        ho = (float)hc[off];
      }
      hnb[off] = (bf16)ho;
    }
  }
}

// ---- head ---------------------------------------------------------------
// r25: 2 blocks per row (k-range split halves the serial loop). grid (256,2).
__global__ void feat_kernel(const bf16* __restrict__ hb0, const int* __restrict__ s1,
                            const int* __restrict__ s2, float* __restrict__ HC,
                            float* __restrict__ H2T) {
  int a = blockIdx.x;
  int half = blockIdx.y;          // 0: k<513, 1: k>=513
  int tid = threadIdx.x;
  __shared__ float red[256];
  const bf16* h1r = hb0 + (size_t)a * HID;
  const bf16* h2r = hb0 + (size_t)(a + 256) * HID;
  float l1 = (float)s1[a] * (1.f / 128.f);
  float l2 = (float)s2[a] * (1.f / 128.f);
  const int k0 = half ? 513 : 0;
  const int k1 = half ? 1025 : 513;
  float dacc = 0.f;
  for (int k = k0 + tid; k < k1; k += 256) {
    float v1 = (k < HID) ? (float)h1r[k] : l1;
    float v2 = (k < HID) ? (float)h2r[k] : l2;
    HC[(size_t)a * HC_W + k] = v1;
    HC[(size_t)a * HC_W + 1025 + k] = v2;
    HC[(size_t)a * HC_W + 2051 + k] = v1 * v2;
    H2T[(size_t)k * 256 + a] = v2;
    float d = v1 - v2;
    dacc += d * d;
  }
  red[tid] = dacc;
  __syncthreads();
  for (int s = 128; s > 0; s >>= 1) {
    if (tid < s) red[tid] += red[tid + s];
    __syncthreads();
  }
  if (tid == 0) {
    // two blocks contribute h_dist partials: block0 writes, block1 adds
    if (half == 0) HC[(size_t)a * HC_W + 2050] = red[0];
  }
  // block1 must add after block0's write: use a separate slot + later sum.
  // Simpler: store partial to IPC-free slot in H2T tail is unsafe; instead
  // both halves recompute their partial into HC via atomic-free split:
  if (half == 1 && tid == 0) {
    // append partial in unused HC slot of row (col 2050 belongs to h_dist);
    // we stash in H2T's padding area? Not available. Use atomicAdd (device
    // scope, two adders per address, deterministic sum order irrelevant
    // for fp determinism? order varies -> avoid. Instead: second pass in
    // t1? Simplest deterministic: half1 writes to HCpart slot below.
    ((float*)H2T)[(size_t)1025 * 256 + a] = red[0];   // tail scratch (in T1P region? no)
  }
}

// tiny fixup: h_dist = part0 + part1 (256 threads, 1 block)
__global__ void feat_fix(float* __restrict__ HC, const float* __restrict__ H2T) {
  int a = threadIdx.x;
  HC[(size_t)a * HC_W + 2050] += ((const float*)H2T)[(size_t)1025 * 256 + a];
}

// r25: 1 row/block, K-split x4 (z=0..3: 257,256,256,256). grid (5,256,4).
__global__ void t1_kernel(const float* __restrict__ HC, const float* __restrict__ Wh,
                          float* __restrict__ T1p) {
  int j = blockIdx.x * 256 + threadIdx.x;
  int a = blockIdx.y;
  int z = blockIdx.z;
  const int k0 = (z == 0) ? 0 : (257 + 256 * (z - 1));
  const int kn = (z == 0) ? 257 : 256;
  __shared__ float sh[257];
  for (int k = threadIdx.x; k < kn; k += 256)
    sh[k] = HC[(size_t)a * HC_W + k0 + k];
  __syncthreads();
  if (j < 1025) {
    float acc = 0.f;
    for (int k = 0; k < kn; ++k)
      acc += sh[k] * Wh[(size_t)(k0 + k) * 1025 + j];
    T1p[(size_t)z * 256 * 1025 + (size_t)a * 1025 + j] = acc;
  }
}

// r22-proven: 1 row/block, K-split x2 (y: 513/512). Writes IP[z].
__global__ void inter_kernel(const float* __restrict__ T1p,
                             const float* __restrict__ H2T, float* __restrict__ IP) {
  int a = blockIdx.x;
  int z = blockIdx.y;
  int b = threadIdx.x;
  const int k0 = z ? 513 : 0;
  const int kn = z ? 512 : 513;
  const size_t zs = (size_t)256 * 1025;
  __shared__ float sT[513];
  for (int k = threadIdx.x; k < kn; k += 256) {
    size_t off = (size_t)a * 1025 + k0 + k;
    sT[k] = T1p[off] + T1p[off + zs] + T1p[off + 2 * zs] + T1p[off + 3 * zs];
  }
  __syncthreads();
  float acc = 0.f;
  for (int k = 0; k < kn; ++k)
    acc += sT[k] * H2T[(size_t)(k0 + k) * 256 + b];
  IP[(size_t)z * 256 * 256 + (size_t)a * 256 + b] = acc;
}

// r23-proven: 2 rows/block, K-split x8 (z, 417 each; z=7: 413).
// z==7 covers gk in [2919,3332): interaction cols [3076,3332) read from
// IP0+IP1 instead of HC.
__global__ void e1_kernel(const float* __restrict__ HC, const float* __restrict__ W1,
                          const float* __restrict__ IP, float* __restrict__ E1p) {
  int a0 = blockIdx.x * 2;
  int j = blockIdx.y * 256 + threadIdx.x;
  int z = blockIdx.z;
  const int k0 = z * 417;
  const int kn = (z == 7) ? 413 : 417;
  const size_t ips = (size_t)256 * 256;
  __shared__ float sh[2][417];
  for (int idx = threadIdx.x; idx < 2 * kn; idx += 256) {
    int r = (idx >= kn) ? 1 : 0;
    int k = idx - r * kn;
    int gk = k0 + k;
    float v;
    if (z == 7 && gk >= 3076) {
      size_t off = (size_t)(a0 + r) * 256 + (gk - 3076);
      v = IP[off] + IP[off + ips];
    } else {
      v = HC[(size_t)(a0 + r) * HC_W + gk];
    }
    sh[r][k] = v;
  }
  __syncthreads();
  float acc0 = 0.f, acc1 = 0.f;
  for (int k = 0; k < kn; ++k) {
    float w = W1[(size_t)(k0 + k) * 512 + j];
    acc0 += sh[0][k] * w;
    acc1 += sh[1][k] * w;
  }
  float* E1 = E1p + (size_t)z * 256 * 512;
  E1[(size_t)a0 * 512 + j] = acc0;
  E1[(size_t)(a0 + 1) * 512 + j] = acc1;
}

// r23-proven: e1 = relu(sum_{z<8} E1p[z] + b1); then W2 reduce. grid 256.
__global__ void out_kernel(const float* __restrict__ E1p,
                           const float* __restrict__ b1, const float* __restrict__ W2,
                           const float* __restrict__ b2, float* __restrict__ out) {
  int a = blockIdx.x;
  int tid = threadIdx.x;
  __shared__ float red0[256], red1[256];
  const size_t zs = (size_t)256 * 512;
  size_t i0 = (size_t)a * 512 + tid;
  size_t i1 = i0 + 256;
  float s0 = 0.f, s1 = 0.f;
#pragma unroll
  for (int z = 0; z < 8; ++z) {
    s0 += E1p[i0 + z * zs];
    s1 += E1p[i1 + z * zs];
  }
  float v0 = fmaxf(s0 + b1[tid], 0.f);
  float v1 = fmaxf(s1 + b1[tid + 256], 0.f);
  float a0 = v0 * W2[2 * tid] + v1 * W2[2 * (tid + 256)];
  float a1 = v0 * W2[2 * tid + 1] + v1 * W2[2 * (tid + 256) + 1];
  red0[tid] = a0;
  red1[tid] = a1;
  __syncthreads();
  for (int s = 128; s > 0; s >>= 1) {
    if (tid < s) { red0[tid] += red0[tid + s]; red1[tid] += red1[tid + s]; }
    __syncthreads();
  }
  if (tid == 0) {
    out[2 * a] = red0[0] + b2[0];
    out[2 * a + 1] = red1[0] + b2[1];
  }
}

// ---- host ---------------------------------------------------------------
extern "C" void kernel_launch(void* const* d_in, const int* in_sizes, int n_in,
                              void* d_out, int out_size, void* d_ws, size_t ws_size,
                              hipStream_t stream) {
  const int*   input1 = (const int*)d_in[0];
  const int*   input2 = (const int*)d_in[1];
  const int*   seql1  = (const int*)d_in[2];
  const int*   seql2  = (const int*)d_in[3];
  const float* emb    = (const float*)d_in[4];
  const float* lk     = (const float*)d_in[5];
  const float* lbias  = (const float*)d_in[6];
  const float* c1i    = (const float*)d_in[7];
  const float* h1i    = (const float*)d_in[8];
  const float* c2i    = (const float*)d_in[9];
  const float* h2i    = (const float*)d_in[10];
  const float* W_h    = (const float*)d_in[11];
  const float* W1     = (const float*)d_in[12];
  const float* b1     = (const float*)d_in[13];
  const float* W2     = (const float*)d_in[14];
  const float* b2     = (const float*)d_in[15];

  char* ws = (char*)d_ws;
  bf16*     WbT   = (bf16*)(ws + WBT_OFF);
  bf16*     Xb    = (bf16*)(ws + XB_OFF);
  bf16*     Hb    = (bf16*)(ws + HB_OFF);
  float*    biasp = (float*)(ws + BIASP_OFF);
  float*    Cb    = (float*)(ws + CB_OFF);
  float*    HC    = (float*)(ws + HC_OFF);   // aliases Xb (dead after lstm)
  float*    H2T   = (float*)(ws + H2T_OFF);  // + tail scratch row at 1025*256
  float*    T1p   = (float*)(ws + T1P_OFF);
  float*    E1p   = (float*)(ws + E1P_OFF);
  float*    IP    = (float*)(ws + IP_OFF);

  pack_wbt<<<dim3(64, 21), 256, 0, stream>>>(lk, WbT);
  pack_xb<<<dim3(512, 16), 320, 0, stream>>>(input1, input2, emb, Xb);
  pack_misc<<<2048, 256, 0, stream>>>(h1i, h2i, c1i, c2i, lbias, Hb, biasp, Cb);

  for (int t = 0; t < NSTEPS; ++t)
    lstm_step<<<512, 256, 0, stream>>>(Xb, WbT, Hb, biasp, Cb, seql1, seql2, t);

  feat_kernel<<<dim3(256, 2), 256, 0, stream>>>(Hb, seql1, seql2, HC, H2T);
  feat_fix<<<1, 256, 0, stream>>>(HC, H2T);
  t1_kernel<<<dim3(5, 256, 4), 256, 0, stream>>>(HC, W_h, T1p);
  inter_kernel<<<dim3(256, 2), 256, 0, stream>>>(T1p, H2T, IP);
  e1_kernel<<<dim3(128, 2, 8), 256, 0, stream>>>(HC, W1, IP, E1p);
  out_kernel<<<256, 256, 0, stream>>>(E1p, b1, W2, b2, (float*)d_out);
}

// Round 26
// 2108.335 us; speedup vs baseline: 1.1164x; 1.0040x over previous
//
#include <hip/hip_runtime.h>
#include <hip/hip_bf16.h>

typedef __bf16 bf16;
typedef __bf16 bf16x8 __attribute__((ext_vector_type(8)));
typedef float f32x4 __attribute__((ext_vector_type(4)));

#define N_ROWS   512      // rows 0..255 seq1, 256..511 seq2
#define HID      1024
#define KX       320      // EMB=300 padded to 320
#define KTOT     1344     // 320 + 1024
#define NSTEPS   128
#define EMB_D    300
#define HC_W     3332     // 1025+1025+1+1025+256

// workspace layout (bytes) — lstm phase:
#define WBT_OFF   0UL          // bf16 [4096][1344]  (packed p2 order)
#define XB_OFF    11010048UL   // bf16 [128][512][320]
#define HB_OFF    52953088UL   // bf16 [2][512][1024]
#define BIASP_OFF 55050240UL   // f32  [4096] (packed p2 order)
#define CB_OFF    55066624UL   // f32  [512][1024] cell state
// head phase (aliases Xb, dead after the recurrence):
#define HC_OFF    11010048UL   // f32 [256][3332]           ends 14,422,016
#define H2T_OFF   14422016UL   // f32 [1025][256]           ends 15,471,616
#define T1P_OFF   15471616UL   // f32 [4][256][1025]        ends 19,670,016
#define E1P_OFF   19670016UL   // f32 [4][256][512]         ends 21,767,168
#define IP_OFF    21767168UL   // f32 [2][256][256]         ends 22,291,456

// r18-proven: NO cooperative kernel; 128 graph-captured per-step launches.
// r23-proven: lstm_step grid 512 (8 rb x 64 cb), 64x64, 2 blocks/CU optimum.
// r25 lesson: fewer rows/block REDUCES weight reuse in skinny GEMMs ->
// regression (t1 1-row). r26: revert t1/feat to r23; e1 4 rows/block
// (doubles W1 reuse; e1 is L3-BW bound on W1 traffic).

__device__ __forceinline__ float sigm(float x) { return 1.f / (1.f + __expf(-x)); }
__device__ __forceinline__ float tanh_fast(float x) {
  float xc = fminf(fmaxf(x, -15.f), 15.f);
  float e = __expf(2.f * xc);
  return (e - 1.f) / (e + 1.f);
}

// LDS-only barrier (r14-proven): does not drain vmcnt.
__device__ __forceinline__ void lds_barrier() {
  asm volatile("s_waitcnt lgkmcnt(0)" ::: "memory");
  __builtin_amdgcn_sched_barrier(0);
  __builtin_amdgcn_s_barrier();
  __builtin_amdgcn_sched_barrier(0);
}

// ---- pack kernels -------------------------------------------------------
// packed order: p2 = cb*64 + g*16 + c  <->  orig col g*1024 + cb*16 + c
// v3 (r20-proven): LDS-transpose tiles, coalesced reads, contiguous writes.
__global__ void pack_wbt(const float* __restrict__ lk, bf16* __restrict__ wbt) {
  __shared__ float sh[64][65];
  const int px = blockIdx.x;       // cb 0..63
  const int k0 = blockIdx.y * 64;  // 21 tiles
  const int t = threadIdx.x;
  {
    const int kk = t >> 2, g = t & 3;
    const int k = k0 + kk;
    const bool valid = (k < KX) ? (k < EMB_D) : true;
    const int src = (k < KX) ? k : (k - 20);
    const float* base = lk + (size_t)src * 4096 + g * 1024 + px * 16;
#pragma unroll
    for (int c4 = 0; c4 < 4; ++c4) {
      float4 v = valid ? *reinterpret_cast<const float4*>(base + c4 * 4)
                       : float4{0.f, 0.f, 0.f, 0.f};
      sh[kk][g * 16 + c4 * 4 + 0] = v.x;
      sh[kk][g * 16 + c4 * 4 + 1] = v.y;
      sh[kk][g * 16 + c4 * 4 + 2] = v.z;
      sh[kk][g * 16 + c4 * 4 + 3] = v.w;
    }
  }
  __syncthreads();
  {
    const int pl = t >> 2, kq = (t & 3) * 16;
    bf16 ov[16];
#pragma unroll
    for (int j = 0; j < 16; ++j) ov[j] = (bf16)sh[kq + j][pl];
    bf16* dst = wbt + (size_t)(px * 64 + pl) * KTOT + k0 + kq;
#pragma unroll
    for (int j = 0; j < 2; ++j)
      *reinterpret_cast<bf16x8*>(dst + j * 8) =
          *reinterpret_cast<const bf16x8*>(&ov[j * 8]);
  }
}

// vectorized bf16x8 writes; block 320 = 8 timesteps x 40 e-groups (r11-proven)
__global__ void pack_xb(const int* __restrict__ in1, const int* __restrict__ in2,
                        const float* __restrict__ emb, bf16* __restrict__ xb) {
  int r = blockIdx.x;                        // 0..511
  int t = blockIdx.y * 8 + threadIdx.x / 40; // 0..127
  int e8 = threadIdx.x % 40;                 // 0..39 (8 elems each)
  int tok = (r < 256) ? in1[r * 128 + t] : in2[(r - 256) * 128 + t];
  const float* er = emb + (size_t)tok * EMB_D + e8 * 8;
  bf16x8 v;
  if (e8 < 37) {
#pragma unroll
    for (int i = 0; i < 8; ++i) v[i] = (bf16)er[i];
  } else {
#pragma unroll
    for (int i = 0; i < 8; ++i) {
      int e = e8 * 8 + i;
      v[i] = (e < EMB_D) ? (bf16)er[i] : (bf16)0.f;
    }
  }
  *reinterpret_cast<bf16x8*>(&xb[((size_t)t * N_ROWS + r) * KX + e8 * 8]) = v;
}

__global__ void pack_misc(const float* __restrict__ h1i, const float* __restrict__ h2i,
                          const float* __restrict__ c1i, const float* __restrict__ c2i,
                          const float* __restrict__ bias, bf16* __restrict__ hb0,
                          float* __restrict__ biasp, float* __restrict__ Cb) {
  int idx = blockIdx.x * 256 + threadIdx.x;
  if (idx < N_ROWS * HID) {
    int r = idx >> 10, k = idx & 1023;
    float v = (r < 256) ? h1i[(size_t)r * HID + k] : h2i[(size_t)(r - 256) * HID + k];
    hb0[idx] = (bf16)v;
    float cv = (r < 256) ? c1i[(size_t)r * HID + k] : c2i[(size_t)(r - 256) * HID + k];
    Cb[idx] = cv;
  }
  if (idx < 4096) {
    int cb = idx >> 6, g = (idx >> 4) & 3, c = idx & 15;
    biasp[idx] = bias[g * HID + cb * 16 + c];
  }
}

// ---- per-step LSTM kernel (r23-proven, verbatim) ------------------------
__launch_bounds__(256, 2)
__global__ void lstm_step(const bf16* __restrict__ xb, const bf16* __restrict__ wbt,
                          bf16* __restrict__ hb, const float* __restrict__ biasp,
                          float* __restrict__ Cb, const int* __restrict__ s1,
                          const int* __restrict__ s2, int t) {
  __shared__ bf16 As[2][64][64];     // 16 KB, XOR-swizzled 16B chunks
  __shared__ bf16 Bs[2][64][64];     // 16 KB  (total 32 KB)
  const int tid = threadIdx.x;
  const int wave = tid >> 6;
  const int lane = tid & 63;
  const int lrow = lane & 15;
  const int hi = lane >> 4;        // 0..3
  const int l7 = lane & 7;
  const int bid = blockIdx.x;
  const int rb = bid >> 6;         // 0..7
  const int cb = bid & 63;         // 0..63
  const int r0 = rb * 64;

  const int cellabs = cb * 16 + lrow;    // this lane's cell column (0..1023)

  int slen[4];        // per q: row = r0 + wave*16 + hi*4 + q
#pragma unroll
  for (int q = 0; q < 4; ++q) {
    int rr = r0 + wave * 16 + hi * 4 + q;
    slen[q] = (rr < 256) ? s1[rr] : s2[rr - 256];
  }

  float creg[4];      // cell state from global
#pragma unroll
  for (int q = 0; q < 4; ++q) {
    int rr = r0 + wave * 16 + hi * 4 + q;
    creg[q] = Cb[(size_t)rr * HID + cellabs];
  }

  float bv[4];        // bias per gate for this lane's cell
#pragma unroll
  for (int ni = 0; ni < 4; ++ni)
    bv[ni] = biasp[cb * 64 + ni * 16 + lrow];

  // staging: A/B 64 rows x 8 chunks, 4 threads/row, 2 chunks each.
  // XOR swizzle: chunk cc -> col ((cc ^ (row&7)) << 3).
  const int a_r = tid >> 2, a_cb = (tid & 3) * 2;

  const bf16* xt = xb + (size_t)t * N_ROWS * KX;
  const bf16* hc0 = hb + ((size_t)(t & 1) << 19);

  bf16x8 ra[2], rbv2[2];
  auto issue_loads = [&](int nkc) {
    const bf16* asrc = (nkc < 5)
        ? (xt + (size_t)(r0 + a_r) * KX + nkc * 64 + a_cb * 8)
        : (hc0 + ((size_t)(r0 + a_r) << 10) + (nkc * 64 - KX) + a_cb * 8);
#pragma unroll
    for (int q = 0; q < 2; ++q)
      ra[q] = *reinterpret_cast<const bf16x8*>(asrc + q * 8);
    const bf16* bsrc = wbt + (size_t)(cb * 64 + a_r) * KTOT + nkc * 64 + a_cb * 8;
#pragma unroll
    for (int q = 0; q < 2; ++q)
      rbv2[q] = *reinterpret_cast<const bf16x8*>(bsrc + q * 8);
  };
  auto stage_to = [&](int buf) {
#pragma unroll
    for (int q = 0; q < 2; ++q)
      *reinterpret_cast<bf16x8*>(&As[buf][a_r][((a_cb + q) ^ (a_r & 7)) << 3]) = ra[q];
#pragma unroll
    for (int q = 0; q < 2; ++q)
      *reinterpret_cast<bf16x8*>(&Bs[buf][a_r][((a_cb + q) ^ (a_r & 7)) << 3]) = rbv2[q];
  };

  issue_loads(0);
  stage_to(0);
  issue_loads(1);
  __syncthreads();
  int db = 0;

  f32x4 acc[4];
#pragma unroll
  for (int ni = 0; ni < 4; ++ni)
    acc[ni] = f32x4{bv[ni], bv[ni], bv[ni], bv[ni]};

  for (int kc = 0; kc < 21; ++kc) {
    if (kc < 20) stage_to(db ^ 1);
    {
      int nkc = kc + 2;
      if (nkc <= 20) issue_loads(nkc);
    }
    // compute chunk kc: per ks, 1 A-frag + 4 B-frags, 4 MFMAs
#pragma unroll
    for (int ks = 0; ks < 2; ++ks) {
      const int cs = (((ks << 2) | hi) ^ l7) << 3;
      bf16x8 af = *reinterpret_cast<const bf16x8*>(&As[db][wave * 16 + lrow][cs]);
#pragma unroll
      for (int ni = 0; ni < 4; ++ni) {
        bf16x8 bfv = *reinterpret_cast<const bf16x8*>(&Bs[db][ni * 16 + lrow][cs]);
        acc[ni] = __builtin_amdgcn_mfma_f32_16x16x32_bf16(af, bfv, acc[ni], 0, 0, 0);
      }
    }
    lds_barrier();
    db ^= 1;
  }

  // cell update: lane owns 4 rows x 1 cell, all 4 gates in-register (g=ni)
  {
    const bf16* hc = hc0;
    bf16* hnb = hb + (((size_t)(t & 1) << 19) ^ ((size_t)1 << 19));
#pragma unroll
    for (int q = 0; q < 4; ++q) {
      float ig = acc[0][q];
      float jg = acc[1][q];
      float fg = acc[2][q];
      float og = acc[3][q];
      float cn = sigm(fg + 1.f) * creg[q] + sigm(ig) * tanh_fast(jg);
      float hv = tanh_fast(cn) * sigm(og);
      int rr = r0 + wave * 16 + hi * 4 + q;
      size_t off = ((size_t)rr << 10) + cellabs;
      float ho;
      if (t < slen[q]) {
        Cb[off] = cn;
        ho = hv;
      } else {
        ho = (float)hc[off];
      }
      hnb[off] = (bf16)ho;
    }
  }
}

// ---- head ---------------------------------------------------------------
// r23-exact feat (single kernel, grid 256)
__global__ void feat_kernel(const bf16* __restrict__ hb0, const int* __restrict__ s1,
                            const int* __restrict__ s2, float* __restrict__ HC,
                            float* __restrict__ H2T) {
  int a = blockIdx.x;
  int tid = threadIdx.x;
  __shared__ float red[256];
  const bf16* h1r = hb0 + (size_t)a * HID;
  const bf16* h2r = hb0 + (size_t)(a + 256) * HID;
  float l1 = (float)s1[a] * (1.f / 128.f);
  float l2 = (float)s2[a] * (1.f / 128.f);
  float dacc = 0.f;
  for (int k = tid; k < 1025; k += 256) {
    float v1 = (k < HID) ? (float)h1r[k] : l1;
    float v2 = (k < HID) ? (float)h2r[k] : l2;
    HC[(size_t)a * HC_W + k] = v1;
    HC[(size_t)a * HC_W + 1025 + k] = v2;
    HC[(size_t)a * HC_W + 2051 + k] = v1 * v2;
    H2T[(size_t)k * 256 + a] = v2;
    float d = v1 - v2;
    dacc += d * d;
  }
  red[tid] = dacc;
  __syncthreads();
  for (int s = 128; s > 0; s >>= 1) {
    if (tid < s) red[tid] += red[tid + s];
    __syncthreads();
  }
  if (tid == 0) HC[(size_t)a * HC_W + 2050] = red[0];
}

// r22/r23-proven: 2 rows/block, K-split x4 (z=0..3: 257,256,256,256).
__global__ void t1_kernel(const float* __restrict__ HC, const float* __restrict__ Wh,
                          float* __restrict__ T1p) {
  int j = blockIdx.x * 256 + threadIdx.x;
  int a0 = blockIdx.y * 2;
  int z = blockIdx.z;
  const int k0 = (z == 0) ? 0 : (257 + 256 * (z - 1));
  const int kn = (z == 0) ? 257 : 256;
  __shared__ float sh[2][257];
  for (int idx = threadIdx.x; idx < 2 * kn; idx += 256) {
    int r = (idx >= kn) ? 1 : 0;
    int k = idx - r * kn;
    sh[r][k] = HC[(size_t)(a0 + r) * HC_W + k0 + k];
  }
  __syncthreads();
  if (j < 1025) {
    float acc0 = 0.f, acc1 = 0.f;
    for (int k = 0; k < kn; ++k) {
      float w = Wh[(size_t)(k0 + k) * 1025 + j];
      acc0 += sh[0][k] * w;
      acc1 += sh[1][k] * w;
    }
    float* T1 = T1p + (size_t)z * 256 * 1025;
    T1[(size_t)a0 * 1025 + j] = acc0;
    T1[(size_t)(a0 + 1) * 1025 + j] = acc1;
  }
}

// r22-proven: 1 row/block, K-split x2 (y: 513/512). Writes IP[z].
__global__ void inter_kernel(const float* __restrict__ T1p,
                             const float* __restrict__ H2T, float* __restrict__ IP) {
  int a = blockIdx.x;
  int z = blockIdx.y;
  int b = threadIdx.x;
  const int k0 = z ? 513 : 0;
  const int kn = z ? 512 : 513;
  const size_t zs = (size_t)256 * 1025;
  __shared__ float sT[513];
  for (int k = threadIdx.x; k < kn; k += 256) {
    size_t off = (size_t)a * 1025 + k0 + k;
    sT[k] = T1p[off] + T1p[off + zs] + T1p[off + 2 * zs] + T1p[off + 3 * zs];
  }
  __syncthreads();
  float acc = 0.f;
  for (int k = 0; k < kn; ++k)
    acc += sT[k] * H2T[(size_t)(k0 + k) * 256 + b];
  IP[(size_t)z * 256 * 256 + (size_t)a * 256 + b] = acc;
}

// r26: 4 rows/block (2x W1 reuse), K-split x4 (z, 833 each). grid (64, 2, 4).
// z==3 covers gk in [2499,3332): interaction cols [3076,3332) read from
// IP0+IP1 instead of HC.
__global__ void e1_kernel(const float* __restrict__ HC, const float* __restrict__ W1,
                          const float* __restrict__ IP, float* __restrict__ E1p) {
  int a0 = blockIdx.x * 4;
  int j = blockIdx.y * 256 + threadIdx.x;
  int z = blockIdx.z;
  const int k0 = z * 833;
  const size_t ips = (size_t)256 * 256;
  __shared__ float sh[4][833];   // 13,328 B
  for (int idx = threadIdx.x; idx < 4 * 833; idx += 256) {
    int r = idx / 833;
    int k = idx - r * 833;
    int gk = k0 + k;
    float v;
    if (z == 3 && gk >= 3076) {
      size_t off = (size_t)(a0 + r) * 256 + (gk - 3076);
      v = IP[off] + IP[off + ips];
    } else {
      v = HC[(size_t)(a0 + r) * HC_W + gk];
    }
    sh[r][k] = v;
  }
  __syncthreads();
  float acc0 = 0.f, acc1 = 0.f, acc2 = 0.f, acc3 = 0.f;
  for (int k = 0; k < 833; ++k) {
    float w = W1[(size_t)(k0 + k) * 512 + j];
    acc0 += sh[0][k] * w;
    acc1 += sh[1][k] * w;
    acc2 += sh[2][k] * w;
    acc3 += sh[3][k] * w;
  }
  float* E1 = E1p + (size_t)z * 256 * 512;
  E1[(size_t)(a0 + 0) * 512 + j] = acc0;
  E1[(size_t)(a0 + 1) * 512 + j] = acc1;
  E1[(size_t)(a0 + 2) * 512 + j] = acc2;
  E1[(size_t)(a0 + 3) * 512 + j] = acc3;
}

// e1 = relu(sum_{z<4} E1p[z] + b1); then W2 reduce. grid 256.
__global__ void out_kernel(const float* __restrict__ E1p,
                           const float* __restrict__ b1, const float* __restrict__ W2,
                           const float* __restrict__ b2, float* __restrict__ out) {
  int a = blockIdx.x;
  int tid = threadIdx.x;
  __shared__ float red0[256], red1[256];
  const size_t zs = (size_t)256 * 512;
  size_t i0 = (size_t)a * 512 + tid;
  size_t i1 = i0 + 256;
  float s0 = 0.f, s1 = 0.f;
#pragma unroll
  for (int z = 0; z < 4; ++z) {
    s0 += E1p[i0 + z * zs];
    s1 += E1p[i1 + z * zs];
  }
  float v0 = fmaxf(s0 + b1[tid], 0.f);
  float v1 = fmaxf(s1 + b1[tid + 256], 0.f);
  float a0 = v0 * W2[2 * tid] + v1 * W2[2 * (tid + 256)];
  float a1 = v0 * W2[2 * tid + 1] + v1 * W2[2 * (tid + 256) + 1];
  red0[tid] = a0;
  red1[tid] = a1;
  __syncthreads();
  for (int s = 128; s > 0; s >>= 1) {
    if (tid < s) { red0[tid] += red0[tid + s]; red1[tid] += red1[tid + s]; }
    __syncthreads();
  }
  if (tid == 0) {
    out[2 * a] = red0[0] + b2[0];
    out[2 * a + 1] = red1[0] + b2[1];
  }
}

// ---- host ---------------------------------------------------------------
extern "C" void kernel_launch(void* const* d_in, const int* in_sizes, int n_in,
                              void* d_out, int out_size, void* d_ws, size_t ws_size,
                              hipStream_t stream) {
  const int*   input1 = (const int*)d_in[0];
  const int*   input2 = (const int*)d_in[1];
  const int*   seql1  = (const int*)d_in[2];
  const int*   seql2  = (const int*)d_in[3];
  const float* emb    = (const float*)d_in[4];
  const float* lk     = (const float*)d_in[5];
  const float* lbias  = (const float*)d_in[6];
  const float* c1i    = (const float*)d_in[7];
  const float* h1i    = (const float*)d_in[8];
  const float* c2i    = (const float*)d_in[9];
  const float* h2i    = (const float*)d_in[10];
  const float* W_h    = (const float*)d_in[11];
  const float* W1     = (const float*)d_in[12];
  const float* b1     = (const float*)d_in[13];
  const float* W2     = (const float*)d_in[14];
  const float* b2     = (const float*)d_in[15];

  char* ws = (char*)d_ws;
  bf16*     WbT   = (bf16*)(ws + WBT_OFF);
  bf16*     Xb    = (bf16*)(ws + XB_OFF);
  bf16*     Hb    = (bf16*)(ws + HB_OFF);
  float*    biasp = (float*)(ws + BIASP_OFF);
  float*    Cb    = (float*)(ws + CB_OFF);
  float*    HC    = (float*)(ws + HC_OFF);   // aliases Xb (dead after lstm)
  float*    H2T   = (float*)(ws + H2T_OFF);
  float*    T1p   = (float*)(ws + T1P_OFF);
  float*    E1p   = (float*)(ws + E1P_OFF);
  float*    IP    = (float*)(ws + IP_OFF);

  pack_wbt<<<dim3(64, 21), 256, 0, stream>>>(lk, WbT);
  pack_xb<<<dim3(512, 16), 320, 0, stream>>>(input1, input2, emb, Xb);
  pack_misc<<<2048, 256, 0, stream>>>(h1i, h2i, c1i, c2i, lbias, Hb, biasp, Cb);

  for (int t = 0; t < NSTEPS; ++t)
    lstm_step<<<512, 256, 0, stream>>>(Xb, WbT, Hb, biasp, Cb, seql1, seql2, t);

  feat_kernel<<<256, 256, 0, stream>>>(Hb, seql1, seql2, HC, H2T);
  t1_kernel<<<dim3(5, 128, 4), 256, 0, stream>>>(HC, W_h, T1p);
  inter_kernel<<<dim3(256, 2), 256, 0, stream>>>(T1p, H2T, IP);
  e1_kernel<<<dim3(64, 2, 4), 256, 0, stream>>>(HC, W1, IP, E1p);
  out_kernel<<<256, 256, 0, stream>>>(E1p, b1, W2, b2, (float*)d_out);
}

// Round 27
// 2096.288 us; speedup vs baseline: 1.1228x; 1.0057x over previous
//
#include <hip/hip_runtime.h>
#include <hip/hip_bf16.h>

typedef __bf16 bf16;
typedef __bf16 bf16x8 __attribute__((ext_vector_type(8)));
typedef float f32x4 __attribute__((ext_vector_type(4)));

#define N_ROWS   512      // rows 0..255 seq1, 256..511 seq2
#define HID      1024
#define KX       320      // EMB=300 padded to 320
#define KTOT     1344     // 320 + 1024
#define NSTEPS   128
#define EMB_D    300
#define HC_W     3332     // 1025+1025+1+1025+256

// workspace layout (bytes) — lstm phase:
#define WBT_OFF   0UL          // bf16 [4096][1344]  (packed p2 order)
#define XB_OFF    11010048UL   // bf16 [128][512][320]
#define HB_OFF    52953088UL   // bf16 [2][512][1024]
#define BIASP_OFF 55050240UL   // f32  [4096] (packed p2 order)
#define CB_OFF    55066624UL   // f32  [512][1024] cell state
// head phase (aliases Xb, dead after the recurrence):
#define HC_OFF    11010048UL   // f32 [256][3332]           ends 14,422,016
#define H2T_OFF   14422016UL   // f32 [1025][256]           ends 15,471,616
#define T1P_OFF   15471616UL   // f32 [4][256][1025]        ends 19,670,016
#define E1P_OFF   19670016UL   // f32 [8][256][512]         ends 23,864,320
#define IP_OFF    23864320UL   // f32 [2][256][256]         ends 24,388,608

// r27 = r23-exact configuration (the measured optimum, 2103 us):
//   - NO cooperative kernel; 128 graph-captured per-step launches (r18).
//   - lstm_step grid 512 (8 rb x 64 cb), 64x64, 32 KB LDS, 2 blocks/CU.
//   - feat single kernel; t1 2-row x4-split; inter x2 -> IP; e1 2-row x8
//     (62% occ optimum; r26's 4-row reuse variant dropped occ to 21%).

__device__ __forceinline__ float sigm(float x) { return 1.f / (1.f + __expf(-x)); }
__device__ __forceinline__ float tanh_fast(float x) {
  float xc = fminf(fmaxf(x, -15.f), 15.f);
  float e = __expf(2.f * xc);
  return (e - 1.f) / (e + 1.f);
}

// LDS-only barrier (r14-proven): does not drain vmcnt.
__device__ __forceinline__ void lds_barrier() {
  asm volatile("s_waitcnt lgkmcnt(0)" ::: "memory");
  __builtin_amdgcn_sched_barrier(0);
  __builtin_amdgcn_s_barrier();
  __builtin_amdgcn_sched_barrier(0);
}

// ---- pack kernels -------------------------------------------------------
// packed order: p2 = cb*64 + g*16 + c  <->  orig col g*1024 + cb*16 + c
// v3 (r20-proven): LDS-transpose tiles, coalesced reads, contiguous writes.
__global__ void pack_wbt(const float* __restrict__ lk, bf16* __restrict__ wbt) {
  __shared__ float sh[64][65];
  const int px = blockIdx.x;       // cb 0..63
  const int k0 = blockIdx.y * 64;  // 21 tiles
  const int t = threadIdx.x;
  {
    const int kk = t >> 2, g = t & 3;
    const int k = k0 + kk;
    const bool valid = (k < KX) ? (k < EMB_D) : true;
    const int src = (k < KX) ? k : (k - 20);
    const float* base = lk + (size_t)src * 4096 + g * 1024 + px * 16;
#pragma unroll
    for (int c4 = 0; c4 < 4; ++c4) {
      float4 v = valid ? *reinterpret_cast<const float4*>(base + c4 * 4)
                       : float4{0.f, 0.f, 0.f, 0.f};
      sh[kk][g * 16 + c4 * 4 + 0] = v.x;
      sh[kk][g * 16 + c4 * 4 + 1] = v.y;
      sh[kk][g * 16 + c4 * 4 + 2] = v.z;
      sh[kk][g * 16 + c4 * 4 + 3] = v.w;
    }
  }
  __syncthreads();
  {
    const int pl = t >> 2, kq = (t & 3) * 16;
    bf16 ov[16];
#pragma unroll
    for (int j = 0; j < 16; ++j) ov[j] = (bf16)sh[kq + j][pl];
    bf16* dst = wbt + (size_t)(px * 64 + pl) * KTOT + k0 + kq;
#pragma unroll
    for (int j = 0; j < 2; ++j)
      *reinterpret_cast<bf16x8*>(dst + j * 8) =
          *reinterpret_cast<const bf16x8*>(&ov[j * 8]);
  }
}

// vectorized bf16x8 writes; block 320 = 8 timesteps x 40 e-groups (r11-proven)
__global__ void pack_xb(const int* __restrict__ in1, const int* __restrict__ in2,
                        const float* __restrict__ emb, bf16* __restrict__ xb) {
  int r = blockIdx.x;                        // 0..511
  int t = blockIdx.y * 8 + threadIdx.x / 40; // 0..127
  int e8 = threadIdx.x % 40;                 // 0..39 (8 elems each)
  int tok = (r < 256) ? in1[r * 128 + t] : in2[(r - 256) * 128 + t];
  const float* er = emb + (size_t)tok * EMB_D + e8 * 8;
  bf16x8 v;
  if (e8 < 37) {
#pragma unroll
    for (int i = 0; i < 8; ++i) v[i] = (bf16)er[i];
  } else {
#pragma unroll
    for (int i = 0; i < 8; ++i) {
      int e = e8 * 8 + i;
      v[i] = (e < EMB_D) ? (bf16)er[i] : (bf16)0.f;
    }
  }
  *reinterpret_cast<bf16x8*>(&xb[((size_t)t * N_ROWS + r) * KX + e8 * 8]) = v;
}

__global__ void pack_misc(const float* __restrict__ h1i, const float* __restrict__ h2i,
                          const float* __restrict__ c1i, const float* __restrict__ c2i,
                          const float* __restrict__ bias, bf16* __restrict__ hb0,
                          float* __restrict__ biasp, float* __restrict__ Cb) {
  int idx = blockIdx.x * 256 + threadIdx.x;
  if (idx < N_ROWS * HID) {
    int r = idx >> 10, k = idx & 1023;
    float v = (r < 256) ? h1i[(size_t)r * HID + k] : h2i[(size_t)(r - 256) * HID + k];
    hb0[idx] = (bf16)v;
    float cv = (r < 256) ? c1i[(size_t)r * HID + k] : c2i[(size_t)(r - 256) * HID + k];
    Cb[idx] = cv;
  }
  if (idx < 4096) {
    int cb = idx >> 6, g = (idx >> 4) & 3, c = idx & 15;
    biasp[idx] = bias[g * HID + cb * 16 + c];
  }
}

// ---- per-step LSTM kernel (r23-proven, verbatim) ------------------------
__launch_bounds__(256, 2)
__global__ void lstm_step(const bf16* __restrict__ xb, const bf16* __restrict__ wbt,
                          bf16* __restrict__ hb, const float* __restrict__ biasp,
                          float* __restrict__ Cb, const int* __restrict__ s1,
                          const int* __restrict__ s2, int t) {
  __shared__ bf16 As[2][64][64];     // 16 KB, XOR-swizzled 16B chunks
  __shared__ bf16 Bs[2][64][64];     // 16 KB  (total 32 KB)
  const int tid = threadIdx.x;
  const int wave = tid >> 6;
  const int lane = tid & 63;
  const int lrow = lane & 15;
  const int hi = lane >> 4;        // 0..3
  const int l7 = lane & 7;
  const int bid = blockIdx.x;
  const int rb = bid >> 6;         // 0..7
  const int cb = bid & 63;         // 0..63
  const int r0 = rb * 64;

  const int cellabs = cb * 16 + lrow;    // this lane's cell column (0..1023)

  int slen[4];        // per q: row = r0 + wave*16 + hi*4 + q
#pragma unroll
  for (int q = 0; q < 4; ++q) {
    int rr = r0 + wave * 16 + hi * 4 + q;
    slen[q] = (rr < 256) ? s1[rr] : s2[rr - 256];
  }

  float creg[4];      // cell state from global
#pragma unroll
  for (int q = 0; q < 4; ++q) {
    int rr = r0 + wave * 16 + hi * 4 + q;
    creg[q] = Cb[(size_t)rr * HID + cellabs];
  }

  float bv[4];        // bias per gate for this lane's cell
#pragma unroll
  for (int ni = 0; ni < 4; ++ni)
    bv[ni] = biasp[cb * 64 + ni * 16 + lrow];

  // staging: A/B 64 rows x 8 chunks, 4 threads/row, 2 chunks each.
  // XOR swizzle: chunk cc -> col ((cc ^ (row&7)) << 3).
  const int a_r = tid >> 2, a_cb = (tid & 3) * 2;

  const bf16* xt = xb + (size_t)t * N_ROWS * KX;
  const bf16* hc0 = hb + ((size_t)(t & 1) << 19);

  bf16x8 ra[2], rbv2[2];
  auto issue_loads = [&](int nkc) {
    const bf16* asrc = (nkc < 5)
        ? (xt + (size_t)(r0 + a_r) * KX + nkc * 64 + a_cb * 8)
        : (hc0 + ((size_t)(r0 + a_r) << 10) + (nkc * 64 - KX) + a_cb * 8);
#pragma unroll
    for (int q = 0; q < 2; ++q)
      ra[q] = *reinterpret_cast<const bf16x8*>(asrc + q * 8);
    const bf16* bsrc = wbt + (size_t)(cb * 64 + a_r) * KTOT + nkc * 64 + a_cb * 8;
#pragma unroll
    for (int q = 0; q < 2; ++q)
      rbv2[q] = *reinterpret_cast<const bf16x8*>(bsrc + q * 8);
  };
  auto stage_to = [&](int buf) {
#pragma unroll
    for (int q = 0; q < 2; ++q)
      *reinterpret_cast<bf16x8*>(&As[buf][a_r][((a_cb + q) ^ (a_r & 7)) << 3]) = ra[q];
#pragma unroll
    for (int q = 0; q < 2; ++q)
      *reinterpret_cast<bf16x8*>(&Bs[buf][a_r][((a_cb + q) ^ (a_r & 7)) << 3]) = rbv2[q];
  };

  issue_loads(0);
  stage_to(0);
  issue_loads(1);
  __syncthreads();
  int db = 0;

  f32x4 acc[4];
#pragma unroll
  for (int ni = 0; ni < 4; ++ni)
    acc[ni] = f32x4{bv[ni], bv[ni], bv[ni], bv[ni]};

  for (int kc = 0; kc < 21; ++kc) {
    if (kc < 20) stage_to(db ^ 1);
    {
      int nkc = kc + 2;
      if (nkc <= 20) issue_loads(nkc);
    }
    // compute chunk kc: per ks, 1 A-frag + 4 B-frags, 4 MFMAs
#pragma unroll
    for (int ks = 0; ks < 2; ++ks) {
      const int cs = (((ks << 2) | hi) ^ l7) << 3;
      bf16x8 af = *reinterpret_cast<const bf16x8*>(&As[db][wave * 16 + lrow][cs]);
#pragma unroll
      for (int ni = 0; ni < 4; ++ni) {
        bf16x8 bfv = *reinterpret_cast<const bf16x8*>(&Bs[db][ni * 16 + lrow][cs]);
        acc[ni] = __builtin_amdgcn_mfma_f32_16x16x32_bf16(af, bfv, acc[ni], 0, 0, 0);
      }
    }
    lds_barrier();
    db ^= 1;
  }

  // cell update: lane owns 4 rows x 1 cell, all 4 gates in-register (g=ni)
  {
    const bf16* hc = hc0;
    bf16* hnb = hb + (((size_t)(t & 1) << 19) ^ ((size_t)1 << 19));
#pragma unroll
    for (int q = 0; q < 4; ++q) {
      float ig = acc[0][q];
      float jg = acc[1][q];
      float fg = acc[2][q];
      float og = acc[3][q];
      float cn = sigm(fg + 1.f) * creg[q] + sigm(ig) * tanh_fast(jg);
      float hv = tanh_fast(cn) * sigm(og);
      int rr = r0 + wave * 16 + hi * 4 + q;
      size_t off = ((size_t)rr << 10) + cellabs;
      float ho;
      if (t < slen[q]) {
        Cb[off] = cn;
        ho = hv;
      } else {
        ho = (float)hc[off];
      }
      hnb[off] = (bf16)ho;
    }
  }
}

// ---- head ---------------------------------------------------------------
__global__ void feat_kernel(const bf16* __restrict__ hb0, const int* __restrict__ s1,
                            const int* __restrict__ s2, float* __restrict__ HC,
                            float* __restrict__ H2T) {
  int a = blockIdx.x;
  int tid = threadIdx.x;
  __shared__ float red[256];
  const bf16* h1r = hb0 + (size_t)a * HID;
  const bf16* h2r = hb0 + (size_t)(a + 256) * HID;
  float l1 = (float)s1[a] * (1.f / 128.f);
  float l2 = (float)s2[a] * (1.f / 128.f);
  float dacc = 0.f;
  for (int k = tid; k < 1025; k += 256) {
    float v1 = (k < HID) ? (float)h1r[k] : l1;
    float v2 = (k < HID) ? (float)h2r[k] : l2;
    HC[(size_t)a * HC_W + k] = v1;
    HC[(size_t)a * HC_W + 1025 + k] = v2;
    HC[(size_t)a * HC_W + 2051 + k] = v1 * v2;
    H2T[(size_t)k * 256 + a] = v2;
    float d = v1 - v2;
    dacc += d * d;
  }
  red[tid] = dacc;
  __syncthreads();
  for (int s = 128; s > 0; s >>= 1) {
    if (tid < s) red[tid] += red[tid + s];
    __syncthreads();
  }
  if (tid == 0) HC[(size_t)a * HC_W + 2050] = red[0];
}

// r22/r23-proven: 2 rows/block, K-split x4 (z=0..3: 257,256,256,256).
__global__ void t1_kernel(const float* __restrict__ HC, const float* __restrict__ Wh,
                          float* __restrict__ T1p) {
  int j = blockIdx.x * 256 + threadIdx.x;
  int a0 = blockIdx.y * 2;
  int z = blockIdx.z;
  const int k0 = (z == 0) ? 0 : (257 + 256 * (z - 1));
  const int kn = (z == 0) ? 257 : 256;
  __shared__ float sh[2][257];
  for (int idx = threadIdx.x; idx < 2 * kn; idx += 256) {
    int r = (idx >= kn) ? 1 : 0;
    int k = idx - r * kn;
    sh[r][k] = HC[(size_t)(a0 + r) * HC_W + k0 + k];
  }
  __syncthreads();
  if (j < 1025) {
    float acc0 = 0.f, acc1 = 0.f;
    for (int k = 0; k < kn; ++k) {
      float w = Wh[(size_t)(k0 + k) * 1025 + j];
      acc0 += sh[0][k] * w;
      acc1 += sh[1][k] * w;
    }
    float* T1 = T1p + (size_t)z * 256 * 1025;
    T1[(size_t)a0 * 1025 + j] = acc0;
    T1[(size_t)(a0 + 1) * 1025 + j] = acc1;
  }
}

// r22-proven: 1 row/block, K-split x2 (y: 513/512). Writes IP[z].
__global__ void inter_kernel(const float* __restrict__ T1p,
                             const float* __restrict__ H2T, float* __restrict__ IP) {
  int a = blockIdx.x;
  int z = blockIdx.y;
  int b = threadIdx.x;
  const int k0 = z ? 513 : 0;
  const int kn = z ? 512 : 513;
  const size_t zs = (size_t)256 * 1025;
  __shared__ float sT[513];
  for (int k = threadIdx.x; k < kn; k += 256) {
    size_t off = (size_t)a * 1025 + k0 + k;
    sT[k] = T1p[off] + T1p[off + zs] + T1p[off + 2 * zs] + T1p[off + 3 * zs];
  }
  __syncthreads();
  float acc = 0.f;
  for (int k = 0; k < kn; ++k)
    acc += sT[k] * H2T[(size_t)(k0 + k) * 256 + b];
  IP[(size_t)z * 256 * 256 + (size_t)a * 256 + b] = acc;
}

// r23-proven: 2 rows/block, K-split x8 (z, 417 each; z=7: 413).
// z==7 covers gk in [2919,3332): interaction cols [3076,3332) read from
// IP0+IP1 instead of HC.
__global__ void e1_kernel(const float* __restrict__ HC, const float* __restrict__ W1,
                          const float* __restrict__ IP, float* __restrict__ E1p) {
  int a0 = blockIdx.x * 2;
  int j = blockIdx.y * 256 + threadIdx.x;
  int z = blockIdx.z;
  const int k0 = z * 417;
  const int kn = (z == 7) ? 413 : 417;
  const size_t ips = (size_t)256 * 256;
  __shared__ float sh[2][417];
  for (int idx = threadIdx.x; idx < 2 * kn; idx += 256) {
    int r = (idx >= kn) ? 1 : 0;
    int k = idx - r * kn;
    int gk = k0 + k;
    float v;
    if (z == 7 && gk >= 3076) {
      size_t off = (size_t)(a0 + r) * 256 + (gk - 3076);
      v = IP[off] + IP[off + ips];
    } else {
      v = HC[(size_t)(a0 + r) * HC_W + gk];
    }
    sh[r][k] = v;
  }
  __syncthreads();
  float acc0 = 0.f, acc1 = 0.f;
  for (int k = 0; k < kn; ++k) {
    float w = W1[(size_t)(k0 + k) * 512 + j];
    acc0 += sh[0][k] * w;
    acc1 += sh[1][k] * w;
  }
  float* E1 = E1p + (size_t)z * 256 * 512;
  E1[(size_t)a0 * 512 + j] = acc0;
  E1[(size_t)(a0 + 1) * 512 + j] = acc1;
}

// r23-proven: e1 = relu(sum_{z<8} E1p[z] + b1); then W2 reduce. grid 256.
__global__ void out_kernel(const float* __restrict__ E1p,
                           const float* __restrict__ b1, const float* __restrict__ W2,
                           const float* __restrict__ b2, float* __restrict__ out) {
  int a = blockIdx.x;
  int tid = threadIdx.x;
  __shared__ float red0[256], red1[256];
  const size_t zs = (size_t)256 * 512;
  size_t i0 = (size_t)a * 512 + tid;
  size_t i1 = i0 + 256;
  float s0 = 0.f, s1 = 0.f;
#pragma unroll
  for (int z = 0; z < 8; ++z) {
    s0 += E1p[i0 + z * zs];
    s1 += E1p[i1 + z * zs];
  }
  float v0 = fmaxf(s0 + b1[tid], 0.f);
  float v1 = fmaxf(s1 + b1[tid + 256], 0.f);
  float a0 = v0 * W2[2 * tid] + v1 * W2[2 * (tid + 256)];
  float a1 = v0 * W2[2 * tid + 1] + v1 * W2[2 * (tid + 256) + 1];
  red0[tid] = a0;
  red1[tid] = a1;
  __syncthreads();
  for (int s = 128; s > 0; s >>= 1) {
    if (tid < s) { red0[tid] += red0[tid + s]; red1[tid] += red1[tid + s]; }
    __syncthreads();
  }
  if (tid == 0) {
    out[2 * a] = red0[0] + b2[0];
    out[2 * a + 1] = red1[0] + b2[1];
  }
}

// ---- host ---------------------------------------------------------------
extern "C" void kernel_launch(void* const* d_in, const int* in_sizes, int n_in,
                              void* d_out, int out_size, void* d_ws, size_t ws_size,
                              hipStream_t stream) {
  const int*   input1 = (const int*)d_in[0];
  const int*   input2 = (const int*)d_in[1];
  const int*   seql1  = (const int*)d_in[2];
  const int*   seql2  = (const int*)d_in[3];
  const float* emb    = (const float*)d_in[4];
  const float* lk     = (const float*)d_in[5];
  const float* lbias  = (const float*)d_in[6];
  const float* c1i    = (const float*)d_in[7];
  const float* h1i    = (const float*)d_in[8];
  const float* c2i    = (const float*)d_in[9];
  const float* h2i    = (const float*)d_in[10];
  const float* W_h    = (const float*)d_in[11];
  const float* W1     = (const float*)d_in[12];
  const float* b1     = (const float*)d_in[13];
  const float* W2     = (const float*)d_in[14];
  const float* b2     = (const float*)d_in[15];

  char* ws = (char*)d_ws;
  bf16*     WbT   = (bf16*)(ws + WBT_OFF);
  bf16*     Xb    = (bf16*)(ws + XB_OFF);
  bf16*     Hb    = (bf16*)(ws + HB_OFF);
  float*    biasp = (float*)(ws + BIASP_OFF);
  float*    Cb    = (float*)(ws + CB_OFF);
  float*    HC    = (float*)(ws + HC_OFF);   // aliases Xb (dead after lstm)
  float*    H2T   = (float*)(ws + H2T_OFF);
  float*    T1p   = (float*)(ws + T1P_OFF);
  float*    E1p   = (float*)(ws + E1P_OFF);
  float*    IP    = (float*)(ws + IP_OFF);

  pack_wbt<<<dim3(64, 21), 256, 0, stream>>>(lk, WbT);
  pack_xb<<<dim3(512, 16), 320, 0, stream>>>(input1, input2, emb, Xb);
  pack_misc<<<2048, 256, 0, stream>>>(h1i, h2i, c1i, c2i, lbias, Hb, biasp, Cb);

  for (int t = 0; t < NSTEPS; ++t)
    lstm_step<<<512, 256, 0, stream>>>(Xb, WbT, Hb, biasp, Cb, seql1, seql2, t);

  feat_kernel<<<256, 256, 0, stream>>>(Hb, seql1, seql2, HC, H2T);
  t1_kernel<<<dim3(5, 128, 4), 256, 0, stream>>>(HC, W_h, T1p);
  inter_kernel<<<dim3(256, 2), 256, 0, stream>>>(T1p, H2T, IP);
  e1_kernel<<<dim3(128, 2, 8), 256, 0, stream>>>(HC, W1, IP, E1p);
  out_kernel<<<256, 256, 0, stream>>>(E1p, b1, W2, b2, (float*)d_out);
}